// Round 4
// baseline (312.582 us; speedup 1.0000x reference)
//
#include <hip/hip_runtime.h>
#include <hip/hip_fp8.h>
#include <stdint.h>

// x(4096x2048) @ W(2048x2048) + bias + probs, tanh.
static constexpr int MM = 4096;
static constexpr int KK = 2048;
static constexpr int NN = 2048;

typedef float floatx16 __attribute__((ext_vector_type(16)));
typedef _Float16 f16x8 __attribute__((ext_vector_type(8)));
typedef unsigned short u16x8 __attribute__((ext_vector_type(8)));
typedef int intx4 __attribute__((ext_vector_type(4)));
typedef int intx8 __attribute__((ext_vector_type(8)));

__device__ __forceinline__ unsigned char f32_to_e4m3(float x) {
  __hip_fp8_e4m3 q(x);           // OCP e4m3fn, RNE + saturate
  return (unsigned char)q.__x;
}
__device__ __forceinline__ float fast_tanh(float x) {
  float e = __expf(2.0f * x);
  return 1.0f - 2.0f / (e + 1.0f);
}
__device__ __forceinline__ unsigned short f32_to_f16_bits(float x) {
  union { _Float16 h; unsigned short u; } c; c.h = (_Float16)x;  // RNE
  return c.u;
}
__device__ __forceinline__ float f16_bits_to_f32(unsigned short u) {
  union { _Float16 h; unsigned short u; } c; c.u = u;
  return (float)c.h;
}

// ---- Layouts (unchanged from R2, verified absmax 0.0059) -----------------
// hi plane FP16: per row, 64-k groups of eight 16B chunks;
//   phys8 = (c8 + row + (row>>3)) & 7.   (conflict-free)
// lo plane e4m3 of (x - fp16(x)) * 2^11: per row, 64-k groups of four 16B
// chunks, contents permuted to match the e5m2-derived fragments (pi trick):
//   chunk c, byte b <-> k = (c>>1)*32 + (b>>3)*16 + (c&1)*8 + (b&7)
//   phys4 = (c + (row&3) + ((row>>2)&3)) & 3

// ---- Fused pre-pass: blocks [0,2048) split x; [2048,3072) split W;
//      [3072,3080) probs+bias.  (UNCHANGED)
__global__ __launch_bounds__(256) void prepass_kernel(
    const float* __restrict__ x, const float* __restrict__ E,
    const float* __restrict__ W, const float* __restrict__ cb,
    unsigned short* __restrict__ ahi, unsigned char* __restrict__ al8,
    unsigned short* __restrict__ bhi, unsigned char* __restrict__ bl8,
    float* __restrict__ bias2) {
  __shared__ float tile[64][65];
  const int blk = blockIdx.x;
  const int tid = threadIdx.x;

  if (blk < 2048) {
    int idx = blk * 256 + tid;
    int row = idx >> 7;        // 128 units per row
    int u = idx & 127;
    int g = u >> 2;            // 64-k group
    int q = u & 3;             // 16-k quarter within group
    const float4* s = (const float4*)(x + (size_t)row * KK + u * 16);
    float v[16];
#pragma unroll
    for (int p = 0; p < 4; p++) {
      float4 t = s[p];
      v[p * 4 + 0] = t.x; v[p * 4 + 1] = t.y; v[p * 4 + 2] = t.z; v[p * 4 + 3] = t.w;
    }
    unsigned short h[16];
    union { unsigned char b[16]; unsigned long long d[2]; } loq;
#pragma unroll
    for (int e = 0; e < 16; e++) {
      h[e] = f32_to_f16_bits(v[e]);
      float lo = v[e] - f16_bits_to_f32(h[e]);
      loq.b[e] = f32_to_e4m3(lo * 2048.0f);
    }
    size_t rb = (size_t)row * KK;
#pragma unroll
    for (int cc = 0; cc < 2; cc++) {
      int c8 = q * 2 + cc;
      int phys8 = (c8 + row + (row >> 3)) & 7;
      u16x8 o;
#pragma unroll
      for (int e = 0; e < 8; e++) o[e] = h[cc * 8 + e];
      *(u16x8*)(ahi + rb + g * 64 + phys8 * 8) = o;
    }
    {
      int sw = (row & 3) + ((row >> 2) & 3);
      int cA = (q >> 1) * 2;
      char* lb = (char*)al8 + rb + g * 64;
      *(unsigned long long*)(lb + (((cA + 0) + sw) & 3) * 16 + (q & 1) * 8) = loq.d[0];
      *(unsigned long long*)(lb + (((cA + 1) + sw) & 3) * 16 + (q & 1) * 8) = loq.d[1];
    }
  } else if (blk < 3072) {
    const int wb = blk - 2048;
    const int n0 = (wb & 31) * 64;
    const int k0 = (wb >> 5) * 64;    // 64-aligned -> one swizzle group
#pragma unroll
    for (int i = 0; i < 4; i++) {
      int t = tid + i * 256;
      int kr = t >> 4;
      int nc = (t & 15) * 4;
      const float4 vv = *(const float4*)(W + (size_t)(k0 + kr) * NN + n0 + nc);
      tile[nc + 0][kr] = vv.x;
      tile[nc + 1][kr] = vv.y;
      tile[nc + 2][kr] = vv.z;
      tile[nc + 3][kr] = vv.w;
    }
    __syncthreads();
    const int nl = tid >> 2;       // 0..63 local n
    const int q = tid & 3;         // 16-k quarter
    const int n = n0 + nl;
    float v[16];
    unsigned short h[16];
    union { unsigned char b[16]; unsigned long long d[2]; } loq;
#pragma unroll
    for (int e = 0; e < 16; e++) {
      v[e] = tile[nl][q * 16 + e];
      h[e] = f32_to_f16_bits(v[e]);
      float lo = v[e] - f16_bits_to_f32(h[e]);
      loq.b[e] = f32_to_e4m3(lo * 2048.0f);
    }
    size_t rb = (size_t)n * KK + k0;
#pragma unroll
    for (int cc = 0; cc < 2; cc++) {
      int c8 = q * 2 + cc;
      int phys8 = (c8 + n + (n >> 3)) & 7;
      u16x8 o;
#pragma unroll
      for (int e = 0; e < 8; e++) o[e] = h[cc * 8 + e];
      *(u16x8*)(bhi + rb + phys8 * 8) = o;
    }
    {
      int sw = (n & 3) + ((n >> 2) & 3);
      int cA = (q >> 1) * 2;
      char* lb = (char*)bl8 + rb;
      *(unsigned long long*)(lb + (((cA + 0) + sw) & 3) * 16 + (q & 1) * 8) = loq.d[0];
      *(unsigned long long*)(lb + (((cA + 1) + sw) & 3) * 16 + (q & 1) * 8) = loq.d[1];
    }
  } else {
    int i = (blk - 3072) * 256 + tid;
    if (i < NN) {
      float p = 1.0f / 2048.0f;
#pragma unroll
      for (int d = 0; d < 9; d++) {
        const float4 a = *(const float4*)(E + (size_t)d * (2048 * 2048) + (size_t)i * 2048);
        float c0 = cosf(a.x), c1 = cosf(a.y), c2 = cosf(a.z);
        p *= (c0 * c0) * (c1 * c1) * (c2 * c2);
      }
      bias2[i] = cb[i] + p;
    }
  }
}

// ---- Main GEMM ----------------------------------------------------------
// R4: 128m x 256n tile, 512 threads (8 waves of 64x64, 2m x 4n).
// hi planes double-buffered in LDS (96 KB total -> proven envelope);
// lo correction fragments staged GLOBAL->VGPR directly (per-lane private:
// no LDS, no barrier, no extra wait phase).  Per K-step, issue order:
//   [8 lo loads(k)] [6 GLL hi(k+1)] vmcnt(14)=hi(k) landed -> barrier ->
//   hi MFMAs + e5m2-perm + correction MFMAs (compiler waits lo at ~vmcnt(6)).
// Counted vmcnt never drains to 0 in-loop.  Grid 256 = 1 block/CU;
// bn = (id&7)*256 pins a constant 1.5 MB B panel per XCD L2.
#define GLL(dst, src)                                                        \
  __builtin_amdgcn_global_load_lds(                                          \
      (const __attribute__((address_space(1))) void*)(src),                  \
      (__attribute__((address_space(3))) void*)(dst), 16, 0, 0)

#define BODY(CUR, NXT, KLO, KNX)                                               \
  {                                                                            \
    __builtin_amdgcn_s_barrier(); /* E: compute(k-1) done -> NXT writable */   \
    __builtin_amdgcn_sched_barrier(0);                                         \
    /* lo(k): 8 direct global->VGPR loads (issued BEFORE hi GLLs so the   */   \
    /* in-order vmcnt retirement lets us wait lo without draining hi(k+1))*/   \
    intx4 la[2][2], lb[2][2];                                                  \
    _Pragma("unroll") for (int t = 0; t < 2; t++)                              \
      _Pragma("unroll") for (int c = 0; c < 2; c++) {                          \
        la[t][c] = *(const intx4*)(aloP[t][c] + (KLO));                        \
        lb[t][c] = *(const intx4*)(bloP[t][c] + (KLO));                        \
      }                                                                        \
    __builtin_amdgcn_sched_barrier(0);                                         \
    /* hi(k+1): 6 GLLs into the other buffer */                                \
    _Pragma("unroll") for (int p = 0; p < 2; p++)                              \
      GLL(&sAh[NXT][p * 4096 + lds16], Ahi + a16 + (size_t)(KNX) + (size_t)(64 * p) * KK); \
    _Pragma("unroll") for (int p = 0; p < 4; p++)                              \
      GLL(&sBh[NXT][p * 4096 + lds16], Bhi + b16 + (size_t)(KNX) + (size_t)(64 * p) * KK); \
    asm volatile("s_waitcnt vmcnt(14)" ::: "memory"); /* hi(k) landed */       \
    __builtin_amdgcn_sched_barrier(0);                                         \
    __builtin_amdgcn_s_barrier(); /* F: hi(k) visible to all waves */          \
    __builtin_amdgcn_sched_barrier(0);                                         \
    intx8 fa8[2], fb8[2];                                                      \
    __builtin_amdgcn_s_setprio(1);                                             \
    _Pragma("unroll") for (int s = 0; s < 4; s++) {                            \
      f16x8 fa[2], fb[2];                                                      \
      _Pragma("unroll") for (int t = 0; t < 2; t++) {                          \
        fa[t] = *(const f16x8*)(sAhB + (CUR) * 16384 + aho[s][t]);             \
        fb[t] = *(const f16x8*)(sBhB + (CUR) * 32768 + bho[s][t]);             \
      }                                                                        \
      _Pragma("unroll") for (int i = 0; i < 2; i++)                            \
        _Pragma("unroll") for (int j = 0; j < 2; j++)                          \
          acc[i][j] = __builtin_amdgcn_mfma_f32_32x32x16_f16(fa[i], fb[j], acc[i][j], 0, 0, 0); \
      _Pragma("unroll") for (int t = 0; t < 2; t++) {                          \
        const uint4 ua = *(const uint4*)&fa[t];                                \
        fa8[t][2 * s]     = (int)__builtin_amdgcn_perm(ua.y, ua.x, 0x07050301u); \
        fa8[t][2 * s + 1] = (int)__builtin_amdgcn_perm(ua.w, ua.z, 0x07050301u); \
        const uint4 ub = *(const uint4*)&fb[t];                                \
        fb8[t][2 * s]     = (int)__builtin_amdgcn_perm(ub.y, ub.x, 0x07050301u); \
        fb8[t][2 * s + 1] = (int)__builtin_amdgcn_perm(ub.w, ub.z, 0x07050301u); \
      }                                                                        \
    }                                                                          \
    intx8 fal[2], fbl[2];                                                      \
    _Pragma("unroll") for (int t = 0; t < 2; t++) {                            \
      ((intx4*)&fal[t])[0] = la[t][0];                                         \
      ((intx4*)&fal[t])[1] = la[t][1];                                         \
      ((intx4*)&fbl[t])[0] = lb[t][0];                                         \
      ((intx4*)&fbl[t])[1] = lb[t][1];                                         \
    }                                                                          \
    _Pragma("unroll") for (int i = 0; i < 2; i++)                              \
      _Pragma("unroll") for (int j = 0; j < 2; j++)                            \
        acc[i][j] = __builtin_amdgcn_mfma_scale_f32_32x32x64_f8f6f4(           \
            fal[i], fb8[j], acc[i][j], 0, 1, 0, 0x74747474, 0, 0x7f7f7f7f);    \
    _Pragma("unroll") for (int i = 0; i < 2; i++)                              \
      _Pragma("unroll") for (int j = 0; j < 2; j++)                            \
        acc[i][j] = __builtin_amdgcn_mfma_scale_f32_32x32x64_f8f6f4(           \
            fa8[i], fbl[j], acc[i][j], 1, 0, 0, 0x7f7f7f7f, 0, 0x74747474);    \
    __builtin_amdgcn_s_setprio(0);                                             \
  }

__global__ __launch_bounds__(512, 2) void gemm_tanh_kernel(
    const unsigned short* __restrict__ Ahi, const unsigned char* __restrict__ Al8,
    const unsigned short* __restrict__ Bhi, const unsigned char* __restrict__ Bl8,
    const float* __restrict__ bias2, float* __restrict__ out) {
  __shared__ __align__(16) unsigned short sAh[2][8192];   // 2 x 16 KB (128 rows)
  __shared__ __align__(16) unsigned short sBh[2][16384];  // 2 x 32 KB (256 rows)
  // total 96 KB -> 1 block/CU, 8 waves (2/SIMD)

  const int tid = threadIdx.x;
  const int lane = tid & 63;
  const int wave = tid >> 6;           // 0..7
  const int wm = (wave >> 2) * 64;     // 2 waves in m
  const int wn = (wave & 3) * 64;      // 4 waves in n

  // 256 blocks = 1/CU.  bn fastest -> id%8 (default XCD round-robin) pins a
  // constant B panel per XCD.
  const int id = blockIdx.x;           // 0..255
  const int bm = (id >> 3) * 128;      // 32 m-blocks
  const int bn = (id & 7) * 256;       //  8 n-blocks

  // hi staging: thread t: row t>>3 (+64 per pass), phys chunk t&7
  const size_t a16 = (size_t)(bm + (tid >> 3)) * KK + (tid & 7) * 8;
  const size_t b16 = (size_t)(bn + (tid >> 3)) * KK + (tid & 7) * 8;
  const int lds16 = tid * 8;   // ushort elements (= tid*16 B)

  const int r31 = lane & 31;
  const int half = lane >> 5;

  // ---- hoisted, kt-invariant LDS read byte-offsets (hi planes) ----------
  const char* sAhB = (const char*)(&sAh[0][0]);
  const char* sBhB = (const char*)(&sBh[0][0]);
  int aho[4][2], bho[4][2];
#pragma unroll
  for (int s = 0; s < 4; s++)
#pragma unroll
    for (int t = 0; t < 2; t++) {
      const int rowA = wm + t * 32 + r31;
      aho[s][t] = rowA * 128 + ((2 * s + half + rowA + (rowA >> 3)) & 7) * 16;
      const int rowB = wn + t * 32 + r31;
      bho[s][t] = rowB * 128 + ((2 * s + half + rowB + (rowB >> 3)) & 7) * 16;
    }
  // ---- hoisted per-lane GLOBAL base pointers for lo fragments -----------
  // lo row stride = KK bytes; within-row offset for k-group = k0 + chunk*16.
  const char* aloP[2][2];
  const char* bloP[2][2];
#pragma unroll
  for (int t = 0; t < 2; t++) {
    const int rowA = wm + t * 32 + r31;
    const int swA = (rowA & 3) + ((rowA >> 2) & 3);
    aloP[t][0] = (const char*)Al8 + (size_t)(bm + rowA) * KK + ((half + swA) & 3) * 16;
    aloP[t][1] = (const char*)Al8 + (size_t)(bm + rowA) * KK + ((2 + half + swA) & 3) * 16;
    const int rowB = wn + t * 32 + r31;
    const int swB = (rowB & 3) + ((rowB >> 2) & 3);
    bloP[t][0] = (const char*)Bl8 + (size_t)(bn + rowB) * KK + ((half + swB) & 3) * 16;
    bloP[t][1] = (const char*)Bl8 + (size_t)(bn + rowB) * KK + ((2 + half + swB) & 3) * 16;
  }

  floatx16 acc[2][2];
#pragma unroll
  for (int i = 0; i < 2; i++)
#pragma unroll
    for (int j = 0; j < 2; j++)
#pragma unroll
      for (int r = 0; r < 16; r++) acc[i][j][r] = 0.f;

  // ---- prologue: stage hi tile 0 into buffer 0 (6 loads in flight) ------
#pragma unroll
  for (int p = 0; p < 2; p++)
    GLL(&sAh[0][p * 4096 + lds16], Ahi + a16 + (size_t)(64 * p) * KK);
#pragma unroll
  for (int p = 0; p < 4; p++)
    GLL(&sBh[0][p * 4096 + lds16], Bhi + b16 + (size_t)(64 * p) * KK);

  for (int kt = 0; kt < 32; kt += 2) {
    const int k0 = kt * 64;
    BODY(0, 1, k0, k0 + 64)
    BODY(1, 0, k0 + 64, (kt < 30) ? (k0 + 128) : 0)
  }
  asm volatile("s_waitcnt vmcnt(0)" ::: "memory");

  // 32x32 C/D layout: col=lane&31, row=(reg&3)+8*(reg>>2)+4*(lane>>5)
#pragma unroll
  for (int j = 0; j < 2; j++) {
    int col = bn + wn + j * 32 + r31;
    float b2 = bias2[col];
#pragma unroll
    for (int i = 0; i < 2; i++) {
      int row0 = bm + wm + i * 32 + 4 * half;
#pragma unroll
      for (int r = 0; r < 16; r++) {
        int row = row0 + (r & 3) + 8 * (r >> 2);
        float val = acc[i][j][r] + b2;
        __builtin_nontemporal_store(fast_tanh(val), &out[(size_t)row * NN + col]);
      }
    }
  }
}

// ---- Fallback (ws too small): naive fp32 ---------------------------------
__global__ __launch_bounds__(256) void fallback_gemm(
    const float* __restrict__ x, const float* __restrict__ E,
    const float* __restrict__ W, const float* __restrict__ cb,
    float* __restrict__ out) {
  __shared__ float sA[16][16];
  __shared__ float sB[16][17];
  __shared__ float sbias[16];
  const int tx = threadIdx.x, ty = threadIdx.y;
  const int row = blockIdx.y * 16 + ty;
  const int col = blockIdx.x * 16 + tx;
  if (ty == 0) {
    float p = 1.0f / 2048.0f;
    for (int d = 0; d < 9; d++) {
      const float* a = E + (size_t)d * (2048 * 2048) + (size_t)col * 2048;
      for (int t = 0; t < 3; t++) { float c = cosf(a[t]); p *= c * c; }
    }
    sbias[tx] = p + cb[col];
  }
  float acc = 0.f;
  for (int k0 = 0; k0 < KK; k0 += 16) {
    __syncthreads();
    sA[ty][tx] = x[(size_t)row * KK + k0 + tx];
    sB[ty][tx] = W[(size_t)(k0 + ty) * NN + col];
    __syncthreads();
#pragma unroll
    for (int kk = 0; kk < 16; kk++) acc += sA[ty][kk] * sB[kk][tx];
  }
  out[(size_t)row * NN + col] = tanhf(acc + sbias[tx]);
}

extern "C" void kernel_launch(void* const* d_in, const int* in_sizes, int n_in,
                              void* d_out, int out_size, void* d_ws, size_t ws_size,
                              hipStream_t stream) {
  const float* x  = (const float*)d_in[0];
  const float* E  = (const float*)d_in[1];  // eternal_weights (9,2048,2048)
  const float* W  = (const float*)d_in[3];  // classical_weights (2048,2048)
  const float* cb = (const float*)d_in[4];  // classical_biases (2048,)
  float* out = (float*)d_out;

  const size_t MB = 1024 * 1024;
  const size_t need = 36 * MB + NN * sizeof(float);
  if (ws_size < need) {
    fallback_gemm<<<dim3(NN / 16, MM / 16), dim3(16, 16), 0, stream>>>(x, E, W, cb, out);
    return;
  }

  char* ws = (char*)d_ws;
  unsigned short* Ahi = (unsigned short*)(ws);            // 16 MB (fp16)
  unsigned short* Bhi = (unsigned short*)(ws + 16 * MB);  //  8 MB (fp16)
  unsigned char* Al8  = (unsigned char*)(ws + 24 * MB);   //  8 MB
  unsigned char* Bl8  = (unsigned char*)(ws + 32 * MB);   //  4 MB
  float* bias2 = (float*)(ws + 36 * MB);                  //  8 KB

  prepass_kernel<<<dim3(3080), dim3(256), 0, stream>>>(
      x, E, W, cb, Ahi, Al8, Bhi, Bl8, bias2);
  gemm_tanh_kernel<<<dim3(256), dim3(512), 0, stream>>>(
      Ahi, Al8, Bhi, Bl8, bias2, out);
}

// Round 5
// 312.160 us; speedup vs baseline: 1.0014x; 1.0014x over previous
//
#include <hip/hip_runtime.h>
#include <hip/hip_fp8.h>
#include <stdint.h>

// x(4096x2048) @ W(2048x2048) + bias + probs, tanh.
static constexpr int MM = 4096;
static constexpr int KK = 2048;
static constexpr int NN = 2048;

typedef float floatx16 __attribute__((ext_vector_type(16)));
typedef _Float16 f16x8 __attribute__((ext_vector_type(8)));
typedef unsigned short u16x8 __attribute__((ext_vector_type(8)));
typedef int intx4 __attribute__((ext_vector_type(4)));
typedef int intx8 __attribute__((ext_vector_type(8)));

__device__ __forceinline__ unsigned char f32_to_e4m3(float x) {
  __hip_fp8_e4m3 q(x);           // OCP e4m3fn, RNE + saturate
  return (unsigned char)q.__x;
}
__device__ __forceinline__ float fast_tanh(float x) {
  float e = __expf(2.0f * x);
  return 1.0f - 2.0f / (e + 1.0f);
}
__device__ __forceinline__ unsigned short f32_to_f16_bits(float x) {
  union { _Float16 h; unsigned short u; } c; c.h = (_Float16)x;  // RNE
  return c.u;
}
__device__ __forceinline__ float f16_bits_to_f32(unsigned short u) {
  union { _Float16 h; unsigned short u; } c; c.u = u;
  return (float)c.h;
}

// ---- Layouts (unchanged, verified absmax 0.0059) -------------------------
// hi plane FP16: per row, 64-k groups of eight 16B chunks;
//   phys8 = (c8 + row + (row>>3)) & 7.
// lo plane e4m3 of (x - fp16(x)) * 2^11: per row, 64-k groups of four 16B
// chunks, contents permuted to match the e5m2-derived fragments (pi trick):
//   chunk c, byte b <-> k = (c>>1)*32 + (b>>3)*16 + (c&1)*8 + (b&7)
//   phys4 = (c + (row&3) + ((row>>2)&3)) & 3

// ---- Fused pre-pass (UNCHANGED) ------------------------------------------
__global__ __launch_bounds__(256) void prepass_kernel(
    const float* __restrict__ x, const float* __restrict__ E,
    const float* __restrict__ W, const float* __restrict__ cb,
    unsigned short* __restrict__ ahi, unsigned char* __restrict__ al8,
    unsigned short* __restrict__ bhi, unsigned char* __restrict__ bl8,
    float* __restrict__ bias2) {
  __shared__ float tile[64][65];
  const int blk = blockIdx.x;
  const int tid = threadIdx.x;

  if (blk < 2048) {
    int idx = blk * 256 + tid;
    int row = idx >> 7;        // 128 units per row
    int u = idx & 127;
    int g = u >> 2;            // 64-k group
    int q = u & 3;             // 16-k quarter within group
    const float4* s = (const float4*)(x + (size_t)row * KK + u * 16);
    float v[16];
#pragma unroll
    for (int p = 0; p < 4; p++) {
      float4 t = s[p];
      v[p * 4 + 0] = t.x; v[p * 4 + 1] = t.y; v[p * 4 + 2] = t.z; v[p * 4 + 3] = t.w;
    }
    unsigned short h[16];
    union { unsigned char b[16]; unsigned long long d[2]; } loq;
#pragma unroll
    for (int e = 0; e < 16; e++) {
      h[e] = f32_to_f16_bits(v[e]);
      float lo = v[e] - f16_bits_to_f32(h[e]);
      loq.b[e] = f32_to_e4m3(lo * 2048.0f);
    }
    size_t rb = (size_t)row * KK;
#pragma unroll
    for (int cc = 0; cc < 2; cc++) {
      int c8 = q * 2 + cc;
      int phys8 = (c8 + row + (row >> 3)) & 7;
      u16x8 o;
#pragma unroll
      for (int e = 0; e < 8; e++) o[e] = h[cc * 8 + e];
      *(u16x8*)(ahi + rb + g * 64 + phys8 * 8) = o;
    }
    {
      int sw = (row & 3) + ((row >> 2) & 3);
      int cA = (q >> 1) * 2;
      char* lb = (char*)al8 + rb + g * 64;
      *(unsigned long long*)(lb + (((cA + 0) + sw) & 3) * 16 + (q & 1) * 8) = loq.d[0];
      *(unsigned long long*)(lb + (((cA + 1) + sw) & 3) * 16 + (q & 1) * 8) = loq.d[1];
    }
  } else if (blk < 3072) {
    const int wb = blk - 2048;
    const int n0 = (wb & 31) * 64;
    const int k0 = (wb >> 5) * 64;    // 64-aligned -> one swizzle group
#pragma unroll
    for (int i = 0; i < 4; i++) {
      int t = tid + i * 256;
      int kr = t >> 4;
      int nc = (t & 15) * 4;
      const float4 vv = *(const float4*)(W + (size_t)(k0 + kr) * NN + n0 + nc);
      tile[nc + 0][kr] = vv.x;
      tile[nc + 1][kr] = vv.y;
      tile[nc + 2][kr] = vv.z;
      tile[nc + 3][kr] = vv.w;
    }
    __syncthreads();
    const int nl = tid >> 2;       // 0..63 local n
    const int q = tid & 3;         // 16-k quarter
    const int n = n0 + nl;
    float v[16];
    unsigned short h[16];
    union { unsigned char b[16]; unsigned long long d[2]; } loq;
#pragma unroll
    for (int e = 0; e < 16; e++) {
      v[e] = tile[nl][q * 16 + e];
      h[e] = f32_to_f16_bits(v[e]);
      float lo = v[e] - f16_bits_to_f32(h[e]);
      loq.b[e] = f32_to_e4m3(lo * 2048.0f);
    }
    size_t rb = (size_t)n * KK + k0;
#pragma unroll
    for (int cc = 0; cc < 2; cc++) {
      int c8 = q * 2 + cc;
      int phys8 = (c8 + n + (n >> 3)) & 7;
      u16x8 o;
#pragma unroll
      for (int e = 0; e < 8; e++) o[e] = h[cc * 8 + e];
      *(u16x8*)(bhi + rb + phys8 * 8) = o;
    }
    {
      int sw = (n & 3) + ((n >> 2) & 3);
      int cA = (q >> 1) * 2;
      char* lb = (char*)bl8 + rb;
      *(unsigned long long*)(lb + (((cA + 0) + sw) & 3) * 16 + (q & 1) * 8) = loq.d[0];
      *(unsigned long long*)(lb + (((cA + 1) + sw) & 3) * 16 + (q & 1) * 8) = loq.d[1];
    }
  } else {
    int i = (blk - 3072) * 256 + tid;
    if (i < NN) {
      float p = 1.0f / 2048.0f;
#pragma unroll
      for (int d = 0; d < 9; d++) {
        const float4 a = *(const float4*)(E + (size_t)d * (2048 * 2048) + (size_t)i * 2048);
        float c0 = cosf(a.x), c1 = cosf(a.y), c2 = cosf(a.z);
        p *= (c0 * c0) * (c1 * c1) * (c2 * c2);
      }
      bias2[i] = cb[i] + p;
    }
  }
}

// ---- Main GEMM ----------------------------------------------------------
// R5: same protocol as R4 (ran, verified), compute phase restructured into a
// 2-deep in-source pipeline: ds_reads for s+2 issue while MFMAs of s run, so
// the LDS port and the MFMA pipe overlap and the 2 waves/SIMD drift into
// complementary roles.  setprio(1) wraps only MFMA clusters (T5 role-split).
#define GLL(dst, src)                                                        \
  __builtin_amdgcn_global_load_lds(                                          \
      (const __attribute__((address_space(1))) void*)(src),                  \
      (__attribute__((address_space(3))) void*)(dst), 16, 0, 0)

#define RD(S, CUR)                                                             \
  _Pragma("unroll") for (int t = 0; t < 2; t++) {                              \
    fa[S][t] = *(const f16x8*)(sAhB + (CUR) * 16384 + aho[S][t]);              \
    fb[S][t] = *(const f16x8*)(sBhB + (CUR) * 32768 + bho[S][t]);              \
  }

#define PERM(S)                                                                \
  _Pragma("unroll") for (int t = 0; t < 2; t++) {                              \
    const uint4 ua = *(const uint4*)&fa[S][t];                                 \
    fa8[t][2 * (S)]     = (int)__builtin_amdgcn_perm(ua.y, ua.x, 0x07050301u); \
    fa8[t][2 * (S) + 1] = (int)__builtin_amdgcn_perm(ua.w, ua.z, 0x07050301u); \
    const uint4 ub = *(const uint4*)&fb[S][t];                                 \
    fb8[t][2 * (S)]     = (int)__builtin_amdgcn_perm(ub.y, ub.x, 0x07050301u); \
    fb8[t][2 * (S) + 1] = (int)__builtin_amdgcn_perm(ub.w, ub.z, 0x07050301u); \
  }

#define MFMA4(S)                                                               \
  __builtin_amdgcn_s_setprio(1);                                               \
  _Pragma("unroll") for (int i = 0; i < 2; i++)                                \
    _Pragma("unroll") for (int j = 0; j < 2; j++)                              \
      acc[i][j] = __builtin_amdgcn_mfma_f32_32x32x16_f16(fa[S][i], fb[S][j],   \
                                                         acc[i][j], 0, 0, 0); \
  __builtin_amdgcn_s_setprio(0);

#define BODY(CUR, NXT, KLO, KNX)                                               \
  {                                                                            \
    __builtin_amdgcn_s_barrier(); /* E: compute(k-1) done -> NXT writable */   \
    __builtin_amdgcn_sched_barrier(0);                                         \
    /* lo(k): 8 direct global->VGPR loads, issued BEFORE the hi GLLs so    */  \
    /* in-order vmcnt retirement lets us wait lo without draining hi(k+1). */  \
    intx4 la[2][2], lb[2][2];                                                  \
    _Pragma("unroll") for (int t = 0; t < 2; t++)                              \
      _Pragma("unroll") for (int c = 0; c < 2; c++) {                          \
        la[t][c] = *(const intx4*)(aloP[t][c] + (KLO));                        \
        lb[t][c] = *(const intx4*)(bloP[t][c] + (KLO));                        \
      }                                                                        \
    __builtin_amdgcn_sched_barrier(0);                                         \
    /* hi(k+1): 6 GLLs into the other buffer */                                \
    _Pragma("unroll") for (int p = 0; p < 2; p++)                              \
      GLL(&sAh[NXT][p * 4096 + lds16], Ahi + a16 + (size_t)(KNX) + (size_t)(64 * p) * KK); \
    _Pragma("unroll") for (int p = 0; p < 4; p++)                              \
      GLL(&sBh[NXT][p * 4096 + lds16], Bhi + b16 + (size_t)(KNX) + (size_t)(64 * p) * KK); \
    asm volatile("s_waitcnt vmcnt(14)" ::: "memory"); /* hi(k) landed */       \
    __builtin_amdgcn_sched_barrier(0);                                         \
    __builtin_amdgcn_s_barrier(); /* F: hi(k) visible to all waves */          \
    __builtin_amdgcn_sched_barrier(0);                                         \
    /* ---- 2-deep pipelined compute: reads(s+2) overlap MFMAs(s) ---- */      \
    f16x8 fa[4][2], fb[4][2];                                                  \
    intx8 fa8[2], fb8[2];                                                      \
    RD(0, CUR) RD(1, CUR)                                                      \
    RD(2, CUR) PERM(0) MFMA4(0)                                                \
    RD(3, CUR) PERM(1) MFMA4(1)                                                \
    PERM(2) MFMA4(2)                                                           \
    PERM(3) MFMA4(3)                                                           \
    intx8 fal[2], fbl[2];                                                      \
    _Pragma("unroll") for (int t = 0; t < 2; t++) {                            \
      ((intx4*)&fal[t])[0] = la[t][0];                                         \
      ((intx4*)&fal[t])[1] = la[t][1];                                         \
      ((intx4*)&fbl[t])[0] = lb[t][0];                                         \
      ((intx4*)&fbl[t])[1] = lb[t][1];                                         \
    }                                                                          \
    __builtin_amdgcn_s_setprio(1);                                             \
    _Pragma("unroll") for (int i = 0; i < 2; i++)                              \
      _Pragma("unroll") for (int j = 0; j < 2; j++)                            \
        acc[i][j] = __builtin_amdgcn_mfma_scale_f32_32x32x64_f8f6f4(           \
            fal[i], fb8[j], acc[i][j], 0, 1, 0, 0x74747474, 0, 0x7f7f7f7f);    \
    _Pragma("unroll") for (int i = 0; i < 2; i++)                              \
      _Pragma("unroll") for (int j = 0; j < 2; j++)                            \
        acc[i][j] = __builtin_amdgcn_mfma_scale_f32_32x32x64_f8f6f4(           \
            fa8[i], fbl[j], acc[i][j], 1, 0, 0, 0x7f7f7f7f, 0, 0x74747474);    \
    __builtin_amdgcn_s_setprio(0);                                             \
  }

__global__ __launch_bounds__(512, 2) void gemm_tanh_kernel(
    const unsigned short* __restrict__ Ahi, const unsigned char* __restrict__ Al8,
    const unsigned short* __restrict__ Bhi, const unsigned char* __restrict__ Bl8,
    const float* __restrict__ bias2, float* __restrict__ out) {
  __shared__ __align__(16) unsigned short sAh[2][8192];   // 2 x 16 KB (128 rows)
  __shared__ __align__(16) unsigned short sBh[2][16384];  // 2 x 32 KB (256 rows)
  // total 96 KB -> 1 block/CU, 8 waves (2/SIMD)

  const int tid = threadIdx.x;
  const int lane = tid & 63;
  const int wave = tid >> 6;           // 0..7
  const int wm = (wave >> 2) * 64;     // 2 waves in m
  const int wn = (wave & 3) * 64;      // 4 waves in n

  // 256 blocks = 1/CU.  bn fastest -> id%8 (default XCD round-robin) pins a
  // constant B panel per XCD.
  const int id = blockIdx.x;           // 0..255
  const int bm = (id >> 3) * 128;      // 32 m-blocks
  const int bn = (id & 7) * 256;       //  8 n-blocks

  // hi staging: thread t: row t>>3 (+64 per pass), phys chunk t&7
  const size_t a16 = (size_t)(bm + (tid >> 3)) * KK + (tid & 7) * 8;
  const size_t b16 = (size_t)(bn + (tid >> 3)) * KK + (tid & 7) * 8;
  const int lds16 = tid * 8;   // ushort elements (= tid*16 B)

  const int r31 = lane & 31;
  const int half = lane >> 5;

  // ---- hoisted, kt-invariant LDS read byte-offsets (hi planes) ----------
  const char* sAhB = (const char*)(&sAh[0][0]);
  const char* sBhB = (const char*)(&sBh[0][0]);
  int aho[4][2], bho[4][2];
#pragma unroll
  for (int s = 0; s < 4; s++)
#pragma unroll
    for (int t = 0; t < 2; t++) {
      const int rowA = wm + t * 32 + r31;
      aho[s][t] = rowA * 128 + ((2 * s + half + rowA + (rowA >> 3)) & 7) * 16;
      const int rowB = wn + t * 32 + r31;
      bho[s][t] = rowB * 128 + ((2 * s + half + rowB + (rowB >> 3)) & 7) * 16;
    }
  // ---- hoisted per-lane GLOBAL base pointers for lo fragments -----------
  const char* aloP[2][2];
  const char* bloP[2][2];
#pragma unroll
  for (int t = 0; t < 2; t++) {
    const int rowA = wm + t * 32 + r31;
    const int swA = (rowA & 3) + ((rowA >> 2) & 3);
    aloP[t][0] = (const char*)Al8 + (size_t)(bm + rowA) * KK + ((half + swA) & 3) * 16;
    aloP[t][1] = (const char*)Al8 + (size_t)(bm + rowA) * KK + ((2 + half + swA) & 3) * 16;
    const int rowB = wn + t * 32 + r31;
    const int swB = (rowB & 3) + ((rowB >> 2) & 3);
    bloP[t][0] = (const char*)Bl8 + (size_t)(bn + rowB) * KK + ((half + swB) & 3) * 16;
    bloP[t][1] = (const char*)Bl8 + (size_t)(bn + rowB) * KK + ((2 + half + swB) & 3) * 16;
  }

  floatx16 acc[2][2];
#pragma unroll
  for (int i = 0; i < 2; i++)
#pragma unroll
    for (int j = 0; j < 2; j++)
#pragma unroll
      for (int r = 0; r < 16; r++) acc[i][j][r] = 0.f;

  // ---- prologue: stage hi tile 0 into buffer 0 (6 loads in flight) ------
#pragma unroll
  for (int p = 0; p < 2; p++)
    GLL(&sAh[0][p * 4096 + lds16], Ahi + a16 + (size_t)(64 * p) * KK);
#pragma unroll
  for (int p = 0; p < 4; p++)
    GLL(&sBh[0][p * 4096 + lds16], Bhi + b16 + (size_t)(64 * p) * KK);

  for (int kt = 0; kt < 32; kt += 2) {
    const int k0 = kt * 64;
    BODY(0, 1, k0, k0 + 64)
    BODY(1, 0, k0 + 64, (kt < 30) ? (k0 + 128) : 0)
  }
  asm volatile("s_waitcnt vmcnt(0)" ::: "memory");

  // 32x32 C/D layout: col=lane&31, row=(reg&3)+8*(reg>>2)+4*(lane>>5)
#pragma unroll
  for (int j = 0; j < 2; j++) {
    int col = bn + wn + j * 32 + r31;
    float b2 = bias2[col];
#pragma unroll
    for (int i = 0; i < 2; i++) {
      int row0 = bm + wm + i * 32 + 4 * half;
#pragma unroll
      for (int r = 0; r < 16; r++) {
        int row = row0 + (r & 3) + 8 * (r >> 2);
        float val = acc[i][j][r] + b2;
        __builtin_nontemporal_store(fast_tanh(val), &out[(size_t)row * NN + col]);
      }
    }
  }
}

// ---- Fallback (ws too small): naive fp32 ---------------------------------
__global__ __launch_bounds__(256) void fallback_gemm(
    const float* __restrict__ x, const float* __restrict__ E,
    const float* __restrict__ W, const float* __restrict__ cb,
    float* __restrict__ out) {
  __shared__ float sA[16][16];
  __shared__ float sB[16][17];
  __shared__ float sbias[16];
  const int tx = threadIdx.x, ty = threadIdx.y;
  const int row = blockIdx.y * 16 + ty;
  const int col = blockIdx.x * 16 + tx;
  if (ty == 0) {
    float p = 1.0f / 2048.0f;
    for (int d = 0; d < 9; d++) {
      const float* a = E + (size_t)d * (2048 * 2048) + (size_t)col * 2048;
      for (int t = 0; t < 3; t++) { float c = cosf(a[t]); p *= c * c; }
    }
    sbias[tx] = p + cb[col];
  }
  float acc = 0.f;
  for (int k0 = 0; k0 < KK; k0 += 16) {
    __syncthreads();
    sA[ty][tx] = x[(size_t)row * KK + k0 + tx];
    sB[ty][tx] = W[(size_t)(k0 + ty) * NN + col];
    __syncthreads();
#pragma unroll
    for (int kk = 0; kk < 16; kk++) acc += sA[ty][kk] * sB[kk][tx];
  }
  out[(size_t)row * NN + col] = tanhf(acc + sbias[tx]);
}

extern "C" void kernel_launch(void* const* d_in, const int* in_sizes, int n_in,
                              void* d_out, int out_size, void* d_ws, size_t ws_size,
                              hipStream_t stream) {
  const float* x  = (const float*)d_in[0];
  const float* E  = (const float*)d_in[1];  // eternal_weights (9,2048,2048)
  const float* W  = (const float*)d_in[3];  // classical_weights (2048,2048)
  const float* cb = (const float*)d_in[4];  // classical_biases (2048,)
  float* out = (float*)d_out;

  const size_t MB = 1024 * 1024;
  const size_t need = 36 * MB + NN * sizeof(float);
  if (ws_size < need) {
    fallback_gemm<<<dim3(NN / 16, MM / 16), dim3(16, 16), 0, stream>>>(x, E, W, cb, out);
    return;
  }

  char* ws = (char*)d_ws;
  unsigned short* Ahi = (unsigned short*)(ws);            // 16 MB (fp16)
  unsigned short* Bhi = (unsigned short*)(ws + 16 * MB);  //  8 MB (fp16)
  unsigned char* Al8  = (unsigned char*)(ws + 24 * MB);   //  8 MB
  unsigned char* Bl8  = (unsigned char*)(ws + 32 * MB);   //  4 MB
  float* bias2 = (float*)(ws + 36 * MB);                  //  8 KB

  prepass_kernel<<<dim3(3080), dim3(256), 0, stream>>>(
      x, E, W, cb, Ahi, Al8, Bhi, Bl8, bias2);
  gemm_tanh_kernel<<<dim3(256), dim3(512), 0, stream>>>(
      Ahi, Al8, Bhi, Bl8, bias2, out);
}

// Round 6
// 296.537 us; speedup vs baseline: 1.0541x; 1.0527x over previous
//
#include <hip/hip_runtime.h>
#include <hip/hip_fp8.h>
#include <stdint.h>

// x(4096x2048) @ W(2048x2048) + bias + probs, tanh.
static constexpr int MM = 4096;
static constexpr int KK = 2048;
static constexpr int NN = 2048;

typedef float floatx16 __attribute__((ext_vector_type(16)));
typedef _Float16 f16x8 __attribute__((ext_vector_type(8)));
typedef unsigned short u16x8 __attribute__((ext_vector_type(8)));
typedef int intx4 __attribute__((ext_vector_type(4)));
typedef int intx8 __attribute__((ext_vector_type(8)));

__device__ __forceinline__ unsigned char f32_to_e4m3(float x) {
  __hip_fp8_e4m3 q(x);           // OCP e4m3fn, RNE + saturate
  return (unsigned char)q.__x;
}
__device__ __forceinline__ float fast_tanh(float x) {
  float e = __expf(2.0f * x);
  return 1.0f - 2.0f / (e + 1.0f);
}
__device__ __forceinline__ unsigned short f32_to_f16_bits(float x) {
  union { _Float16 h; unsigned short u; } c; c.h = (_Float16)x;  // RNE
  return c.u;
}
__device__ __forceinline__ float f16_bits_to_f32(unsigned short u) {
  union { _Float16 h; unsigned short u; } c; c.u = u;
  return (float)c.h;
}

// ---- Layouts (verified absmax 0.0059) ------------------------------------
// hi plane FP16: per row, 64-k groups of eight 16B chunks;
//   phys8 = (c8 + row + (row>>3)) & 7.   (conflict-free)
// lo plane e4m3 of (x - fp16(x)) * 2^11: per row, 64-k groups of four 16B
// chunks, contents permuted to match the e5m2-derived fragments (pi trick):
//   chunk c, byte b <-> k = (c>>1)*32 + (b>>3)*16 + (c&1)*8 + (b&7)
//   phys4 = (c + (row&3) + ((row>>2)&3)) & 3

// ---- Fused pre-pass (UNCHANGED, verified) --------------------------------
__global__ __launch_bounds__(256) void prepass_kernel(
    const float* __restrict__ x, const float* __restrict__ E,
    const float* __restrict__ W, const float* __restrict__ cb,
    unsigned short* __restrict__ ahi, unsigned char* __restrict__ al8,
    unsigned short* __restrict__ bhi, unsigned char* __restrict__ bl8,
    float* __restrict__ bias2) {
  __shared__ float tile[64][65];
  const int blk = blockIdx.x;
  const int tid = threadIdx.x;

  if (blk < 2048) {
    int idx = blk * 256 + tid;
    int row = idx >> 7;        // 128 units per row
    int u = idx & 127;
    int g = u >> 2;            // 64-k group
    int q = u & 3;             // 16-k quarter within group
    const float4* s = (const float4*)(x + (size_t)row * KK + u * 16);
    float v[16];
#pragma unroll
    for (int p = 0; p < 4; p++) {
      float4 t = s[p];
      v[p * 4 + 0] = t.x; v[p * 4 + 1] = t.y; v[p * 4 + 2] = t.z; v[p * 4 + 3] = t.w;
    }
    unsigned short h[16];
    union { unsigned char b[16]; unsigned long long d[2]; } loq;
#pragma unroll
    for (int e = 0; e < 16; e++) {
      h[e] = f32_to_f16_bits(v[e]);
      float lo = v[e] - f16_bits_to_f32(h[e]);
      loq.b[e] = f32_to_e4m3(lo * 2048.0f);
    }
    size_t rb = (size_t)row * KK;
#pragma unroll
    for (int cc = 0; cc < 2; cc++) {
      int c8 = q * 2 + cc;
      int phys8 = (c8 + row + (row >> 3)) & 7;
      u16x8 o;
#pragma unroll
      for (int e = 0; e < 8; e++) o[e] = h[cc * 8 + e];
      *(u16x8*)(ahi + rb + g * 64 + phys8 * 8) = o;
    }
    {
      int sw = (row & 3) + ((row >> 2) & 3);
      int cA = (q >> 1) * 2;
      char* lb = (char*)al8 + rb + g * 64;
      *(unsigned long long*)(lb + (((cA + 0) + sw) & 3) * 16 + (q & 1) * 8) = loq.d[0];
      *(unsigned long long*)(lb + (((cA + 1) + sw) & 3) * 16 + (q & 1) * 8) = loq.d[1];
    }
  } else if (blk < 3072) {
    const int wb = blk - 2048;
    const int n0 = (wb & 31) * 64;
    const int k0 = (wb >> 5) * 64;    // 64-aligned -> one swizzle group
#pragma unroll
    for (int i = 0; i < 4; i++) {
      int t = tid + i * 256;
      int kr = t >> 4;
      int nc = (t & 15) * 4;
      const float4 vv = *(const float4*)(W + (size_t)(k0 + kr) * NN + n0 + nc);
      tile[nc + 0][kr] = vv.x;
      tile[nc + 1][kr] = vv.y;
      tile[nc + 2][kr] = vv.z;
      tile[nc + 3][kr] = vv.w;
    }
    __syncthreads();
    const int nl = tid >> 2;       // 0..63 local n
    const int q = tid & 3;         // 16-k quarter
    const int n = n0 + nl;
    float v[16];
    unsigned short h[16];
    union { unsigned char b[16]; unsigned long long d[2]; } loq;
#pragma unroll
    for (int e = 0; e < 16; e++) {
      v[e] = tile[nl][q * 16 + e];
      h[e] = f32_to_f16_bits(v[e]);
      float lo = v[e] - f16_bits_to_f32(h[e]);
      loq.b[e] = f32_to_e4m3(lo * 2048.0f);
    }
    size_t rb = (size_t)n * KK + k0;
#pragma unroll
    for (int cc = 0; cc < 2; cc++) {
      int c8 = q * 2 + cc;
      int phys8 = (c8 + n + (n >> 3)) & 7;
      u16x8 o;
#pragma unroll
      for (int e = 0; e < 8; e++) o[e] = h[cc * 8 + e];
      *(u16x8*)(bhi + rb + phys8 * 8) = o;
    }
    {
      int sw = (n & 3) + ((n >> 2) & 3);
      int cA = (q >> 1) * 2;
      char* lb = (char*)bl8 + rb;
      *(unsigned long long*)(lb + (((cA + 0) + sw) & 3) * 16 + (q & 1) * 8) = loq.d[0];
      *(unsigned long long*)(lb + (((cA + 1) + sw) & 3) * 16 + (q & 1) * 8) = loq.d[1];
    }
  } else {
    int i = (blk - 3072) * 256 + tid;
    if (i < NN) {
      float p = 1.0f / 2048.0f;
#pragma unroll
      for (int d = 0; d < 9; d++) {
        const float4 a = *(const float4*)(E + (size_t)d * (2048 * 2048) + (size_t)i * 2048);
        float c0 = cosf(a.x), c1 = cosf(a.y), c2 = cosf(a.z);
        p *= (c0 * c0) * (c1 * c1) * (c2 * c2);
      }
      bias2[i] = cb[i] + p;
    }
  }
}

// ---- Main GEMM ----------------------------------------------------------
// R6 = the verified Round-2 structure (128x128 tile, 256 thr, 80 KB LDS,
// 2 blocks/CU, 3-barrier counted-vmcnt protocol) with ONE change: the
// compute phase uses batched ds_reads + counted lgkmcnt(4) inline-asm waits
// + sched_barrier(0) pins (rule #18) so 8 reads stay in flight and phase
// s+1's reads issue under phase s's MFMA shadow.  Global protocol identical.
#define GLL(dst, src)                                                        \
  __builtin_amdgcn_global_load_lds(                                          \
      (const __attribute__((address_space(1))) void*)(src),                  \
      (__attribute__((address_space(3))) void*)(dst), 16, 0, 0)

#define RD(S, CUR)                                                             \
  _Pragma("unroll") for (int t = 0; t < 2; t++) {                              \
    fa[S][t] = *(const f16x8*)(sAhB + (CUR) * 16384 + aho[S][t]);              \
    fb[S][t] = *(const f16x8*)(sBhB + (CUR) * 16384 + bho[S][t]);              \
  }

#define PERM(S)                                                                \
  _Pragma("unroll") for (int t = 0; t < 2; t++) {                              \
    const uint4 ua = *(const uint4*)&fa[S][t];                                 \
    fa8[t][2 * (S)]     = (int)__builtin_amdgcn_perm(ua.y, ua.x, 0x07050301u); \
    fa8[t][2 * (S) + 1] = (int)__builtin_amdgcn_perm(ua.w, ua.z, 0x07050301u); \
    const uint4 ub = *(const uint4*)&fb[S][t];                                 \
    fb8[t][2 * (S)]     = (int)__builtin_amdgcn_perm(ub.y, ub.x, 0x07050301u); \
    fb8[t][2 * (S) + 1] = (int)__builtin_amdgcn_perm(ub.w, ub.z, 0x07050301u); \
  }

#define MFMA4(S)                                                               \
  __builtin_amdgcn_s_setprio(1);                                               \
  _Pragma("unroll") for (int i = 0; i < 2; i++)                                \
    _Pragma("unroll") for (int j = 0; j < 2; j++)                              \
      acc[i][j] = __builtin_amdgcn_mfma_f32_32x32x16_f16(fa[S][i], fb[S][j],   \
                                                         acc[i][j], 0, 0, 0); \
  __builtin_amdgcn_s_setprio(0);

#define LGKM4  asm volatile("s_waitcnt lgkmcnt(4)" ::: "memory");              \
               __builtin_amdgcn_sched_barrier(0);
#define LGKM0  asm volatile("s_waitcnt lgkmcnt(0)" ::: "memory");              \
               __builtin_amdgcn_sched_barrier(0);
#define PIN    __builtin_amdgcn_sched_barrier(0);

#define BODY(CUR, NXT, KLO, KNX)                                               \
  {                                                                            \
    __builtin_amdgcn_s_barrier(); /* E: compute(k-1) done -> NXT writable */   \
    __builtin_amdgcn_sched_barrier(0);                                         \
    /* lo(k): 4 GLLs (single buffer) */                                        \
    _Pragma("unroll") for (int p = 0; p < 2; p++) {                            \
      GLL(&sAl[p * 4096 + lds8], Al8 + a8b + (size_t)(KLO) + (size_t)(64 * p) * KK); \
      GLL(&sBl[p * 4096 + lds8], Bl8 + b8b + (size_t)(KLO) + (size_t)(64 * p) * KK); \
    }                                                                          \
    /* hi(k+1): 8 GLLs into the other buffer */                                \
    _Pragma("unroll") for (int p = 0; p < 4; p++) {                            \
      GLL(&sAh[NXT][p * 2048 + lds16], Ahi + a16 + (size_t)(KNX) + (size_t)(32 * p) * KK); \
      GLL(&sBh[NXT][p * 2048 + lds16], Bhi + b16 + (size_t)(KNX) + (size_t)(32 * p) * KK); \
    }                                                                          \
    asm volatile("s_waitcnt vmcnt(12)" ::: "memory"); /* hi(k) landed */       \
    __builtin_amdgcn_sched_barrier(0);                                         \
    __builtin_amdgcn_s_barrier(); /* F: hi(k) visible to all waves */          \
    __builtin_amdgcn_sched_barrier(0);                                         \
    /* ---- phased hi compute: counted lgkm, 8 reads in flight ---- */         \
    f16x8 fa[4][2], fb[4][2];                                                  \
    intx8 fa8[2], fb8[2];                                                      \
    RD(0, CUR) RD(1, CUR)                                                      \
    LGKM4            /* s0 ready (s1 in flight) */                             \
    RD(2, CUR) PIN                                                             \
    PERM(0) MFMA4(0)                                                           \
    LGKM4            /* s1 ready (s2 in flight) */                             \
    RD(3, CUR) PIN                                                             \
    PERM(1) MFMA4(1)                                                           \
    LGKM4            /* s2 ready (s3 in flight) */                             \
    PERM(2) MFMA4(2)                                                           \
    LGKM0            /* s3 ready */                                            \
    PERM(3) MFMA4(3)                                                           \
    asm volatile("s_waitcnt vmcnt(8)" ::: "memory"); /* lo(k) landed */        \
    __builtin_amdgcn_sched_barrier(0);                                         \
    __builtin_amdgcn_s_barrier(); /* C: lo(k) visible to all waves */          \
    __builtin_amdgcn_sched_barrier(0);                                         \
    intx8 fal[2], fbl[2];                                                      \
    _Pragma("unroll") for (int t = 0; t < 2; t++) {                            \
      ((intx4*)&fal[t])[0] = *(const intx4*)(sAlB + alo[t][0]);                \
      ((intx4*)&fal[t])[1] = *(const intx4*)(sAlB + alo[t][1]);                \
      ((intx4*)&fbl[t])[0] = *(const intx4*)(sBlB + blo[t][0]);                \
      ((intx4*)&fbl[t])[1] = *(const intx4*)(sBlB + blo[t][1]);                \
    }                                                                          \
    LGKM0                                                                      \
    __builtin_amdgcn_s_setprio(1);                                             \
    _Pragma("unroll") for (int i = 0; i < 2; i++)                              \
      _Pragma("unroll") for (int j = 0; j < 2; j++)                            \
        acc[i][j] = __builtin_amdgcn_mfma_scale_f32_32x32x64_f8f6f4(           \
            fal[i], fb8[j], acc[i][j], 0, 1, 0, 0x74747474, 0, 0x7f7f7f7f);    \
    _Pragma("unroll") for (int i = 0; i < 2; i++)                              \
      _Pragma("unroll") for (int j = 0; j < 2; j++)                            \
        acc[i][j] = __builtin_amdgcn_mfma_scale_f32_32x32x64_f8f6f4(           \
            fa8[i], fbl[j], acc[i][j], 1, 0, 0, 0x7f7f7f7f, 0, 0x74747474);    \
    __builtin_amdgcn_s_setprio(0);                                             \
  }

__global__ __launch_bounds__(256, 2) void gemm_tanh_kernel(
    const unsigned short* __restrict__ Ahi, const unsigned char* __restrict__ Al8,
    const unsigned short* __restrict__ Bhi, const unsigned char* __restrict__ Bl8,
    const float* __restrict__ bias2, float* __restrict__ out) {
  __shared__ __align__(16) unsigned short sAh[2][8192];  // 32 KB
  __shared__ __align__(16) unsigned short sBh[2][8192];  // 32 KB
  __shared__ __align__(16) unsigned char sAl[8192];      //  8 KB
  __shared__ __align__(16) unsigned char sBl[8192];      //  8 KB
  // total 80 KB -> 2 blocks/CU (160 KB exactly)

  const int tid = threadIdx.x;
  const int lane = tid & 63;
  const int wave = tid >> 6;
  const int wm = (wave >> 1) * 64;   // wave: 64m x 64n as 2x2 of 32x32
  const int wn = (wave & 1) * 64;

  // 4x4 cluster swizzle: 16 consecutive block ids cover a 512m x 512n
  // super-tile -> shared A/B strips stay hot in the XCD L2s.
  const int id = blockIdx.x;         // 0..511
  const int cid = id >> 4, lid = id & 15;
  const int bm = ((cid >> 2) * 4 + (lid >> 2)) * 128;   // 32 m-blocks
  const int bn = ((cid & 3) * 4 + (lid & 3)) * 128;     // 16 n-blocks

  // hi staging: pass p -> rows 32p..32p+31; thread t: row t>>3, chunk t&7
  const size_t a16 = (size_t)(bm + (tid >> 3)) * KK + (tid & 7) * 8;
  const size_t b16 = (size_t)(bn + (tid >> 3)) * KK + (tid & 7) * 8;
  // lo staging: pass p -> rows 64p..64p+63; thread t: row t>>2, chunk t&3
  const size_t a8b = (size_t)(bm + (tid >> 2)) * KK + (tid & 3) * 16;
  const size_t b8b = (size_t)(bn + (tid >> 2)) * KK + (tid & 3) * 16;
  const int lds16 = tid * 8;   // ushort elements (= tid*16 B)
  const int lds8 = tid * 16;   // bytes

  const int r31 = lane & 31;
  const int half = lane >> 5;

  // ---- hoisted, kt-invariant LDS read byte-offsets ----------------------
  const char* sAhB = (const char*)(&sAh[0][0]);
  const char* sBhB = (const char*)(&sBh[0][0]);
  const char* sAlB = (const char*)(&sAl[0]);
  const char* sBlB = (const char*)(&sBl[0]);
  int aho[4][2], bho[4][2];
#pragma unroll
  for (int s = 0; s < 4; s++)
#pragma unroll
    for (int t = 0; t < 2; t++) {
      const int rowA = wm + t * 32 + r31;
      aho[s][t] = rowA * 128 + ((2 * s + half + rowA + (rowA >> 3)) & 7) * 16;
      const int rowB = wn + t * 32 + r31;
      bho[s][t] = rowB * 128 + ((2 * s + half + rowB + (rowB >> 3)) & 7) * 16;
    }
  int alo[2][2], blo[2][2];
#pragma unroll
  for (int t = 0; t < 2; t++) {
    const int rowA = wm + t * 32 + r31;
    const int swA = (rowA & 3) + ((rowA >> 2) & 3);
    alo[t][0] = rowA * 64 + ((half + swA) & 3) * 16;
    alo[t][1] = rowA * 64 + ((2 + half + swA) & 3) * 16;
    const int rowB = wn + t * 32 + r31;
    const int swB = (rowB & 3) + ((rowB >> 2) & 3);
    blo[t][0] = rowB * 64 + ((half + swB) & 3) * 16;
    blo[t][1] = rowB * 64 + ((2 + half + swB) & 3) * 16;
  }

  floatx16 acc[2][2];
#pragma unroll
  for (int i = 0; i < 2; i++)
#pragma unroll
    for (int j = 0; j < 2; j++)
#pragma unroll
      for (int r = 0; r < 16; r++) acc[i][j][r] = 0.f;

  // ---- prologue: stage hi(k=0) into buffer 0 (8 loads in flight) --------
#pragma unroll
  for (int p = 0; p < 4; p++) {
    GLL(&sAh[0][p * 2048 + lds16], Ahi + a16 + (size_t)(32 * p) * KK);
    GLL(&sBh[0][p * 2048 + lds16], Bhi + b16 + (size_t)(32 * p) * KK);
  }

  for (int kt = 0; kt < 32; kt += 2) {
    const int k0 = kt * 64;
    BODY(0, 1, k0, k0 + 64)
    BODY(1, 0, k0 + 64, (kt < 30) ? (k0 + 128) : 0)
  }
  asm volatile("s_waitcnt vmcnt(0)" ::: "memory");

  // 32x32 C/D layout: col=lane&31, row=(reg&3)+8*(reg>>2)+4*(lane>>5)
#pragma unroll
  for (int j = 0; j < 2; j++) {
    int col = bn + wn + j * 32 + r31;
    float b2 = bias2[col];
#pragma unroll
    for (int i = 0; i < 2; i++) {
      int row0 = bm + wm + i * 32 + 4 * half;
#pragma unroll
      for (int r = 0; r < 16; r++) {
        int row = row0 + (r & 3) + 8 * (r >> 2);
        float val = acc[i][j][r] + b2;
        __builtin_nontemporal_store(fast_tanh(val), &out[(size_t)row * NN + col]);
      }
    }
  }
}

// ---- Fallback (ws too small): naive fp32 ---------------------------------
__global__ __launch_bounds__(256) void fallback_gemm(
    const float* __restrict__ x, const float* __restrict__ E,
    const float* __restrict__ W, const float* __restrict__ cb,
    float* __restrict__ out) {
  __shared__ float sA[16][16];
  __shared__ float sB[16][17];
  __shared__ float sbias[16];
  const int tx = threadIdx.x, ty = threadIdx.y;
  const int row = blockIdx.y * 16 + ty;
  const int col = blockIdx.x * 16 + tx;
  if (ty == 0) {
    float p = 1.0f / 2048.0f;
    for (int d = 0; d < 9; d++) {
      const float* a = E + (size_t)d * (2048 * 2048) + (size_t)col * 2048;
      for (int t = 0; t < 3; t++) { float c = cosf(a[t]); p *= c * c; }
    }
    sbias[tx] = p + cb[col];
  }
  float acc = 0.f;
  for (int k0 = 0; k0 < KK; k0 += 16) {
    __syncthreads();
    sA[ty][tx] = x[(size_t)row * KK + k0 + tx];
    sB[ty][tx] = W[(size_t)(k0 + ty) * NN + col];
    __syncthreads();
#pragma unroll
    for (int kk = 0; kk < 16; kk++) acc += sA[ty][kk] * sB[kk][tx];
  }
  out[(size_t)row * NN + col] = tanhf(acc + sbias[tx]);
}

extern "C" void kernel_launch(void* const* d_in, const int* in_sizes, int n_in,
                              void* d_out, int out_size, void* d_ws, size_t ws_size,
                              hipStream_t stream) {
  const float* x  = (const float*)d_in[0];
  const float* E  = (const float*)d_in[1];  // eternal_weights (9,2048,2048)
  const float* W  = (const float*)d_in[3];  // classical_weights (2048,2048)
  const float* cb = (const float*)d_in[4];  // classical_biases (2048,)
  float* out = (float*)d_out;

  const size_t MB = 1024 * 1024;
  const size_t need = 36 * MB + NN * sizeof(float);
  if (ws_size < need) {
    fallback_gemm<<<dim3(NN / 16, MM / 16), dim3(16, 16), 0, stream>>>(x, E, W, cb, out);
    return;
  }

  char* ws = (char*)d_ws;
  unsigned short* Ahi = (unsigned short*)(ws);            // 16 MB (fp16)
  unsigned short* Bhi = (unsigned short*)(ws + 16 * MB);  //  8 MB (fp16)
  unsigned char* Al8  = (unsigned char*)(ws + 24 * MB);   //  8 MB
  unsigned char* Bl8  = (unsigned char*)(ws + 32 * MB);   //  4 MB
  float* bias2 = (float*)(ws + 36 * MB);                  //  8 KB

  prepass_kernel<<<dim3(3080), dim3(256), 0, stream>>>(
      x, E, W, cb, Ahi, Al8, Bhi, Bl8, bias2);
  gemm_tanh_kernel<<<dim3(512), dim3(256), 0, stream>>>(
      Ahi, Al8, Bhi, Bl8, bias2, out);
}